// Round 3
// baseline (83.019 us; speedup 1.0000x reference)
//
#include <hip/hip_runtime.h>

#define NQ 10
#define NP 81
#define TT 8
#define GB 4     // batch elements per block
#define NT 320   // 5 waves: wave == gate in stage B

__device__ __forceinline__ float sigm(float z) {
    z = fminf(fmaxf(z, -30.f), 30.f);
    return 1.f / (1.f + __expf(-z));
}
__device__ __forceinline__ float tanh_(float z) {
    z = fminf(fmaxf(z, -15.f), 15.f);
    float e = __expf(2.f * z);
    return (e - 1.f) / (e + 1.f);
}

// 512 blocks x 320 threads; block = 4 batch elements through the T=8 scan.
// Per timestep (4 intra-block barriers):
//   P1: p[g][81] = px[t] (regs, hoisted x@Wx+b) + h@Wh   (thread=(g,col))
//   A : 256 threads each do ONE __sincosf of one circuit angle -> sc_s
//   B : wave==gate (no divergence): assemble 30 closed-form features from
//       sc_s (~60 flops) + dot-30 with R rows held in regs (40 lanes/wave)
//   C : LSTM cell update (40 threads)
__global__ __launch_bounds__(NT) void qlstm_kernel(
    const float* __restrict__ x, const float* __restrict__ Wx,
    const float* __restrict__ Wh, const float* __restrict__ bias,
    const float* __restrict__ R, float* __restrict__ out) {

    __shared__ float x_s[GB * TT * NQ];   // 320
    __shared__ float p_s[GB * NP];        // 324
    __shared__ float2 sc_s[GB][64];       // (sin,cos) per angle unit
    __shared__ float g_s[5 * GB * NQ];    // [gate][g][k]
    __shared__ float h_s[GB * NQ];
    __shared__ float c_s[GB * NQ];

    const int tid = threadIdx.x;
    const int bbase = blockIdx.x * GB;
    const int wv = __builtin_amdgcn_readfirstlane(tid >> 6);
    const int ln = tid & 63;

    // ---- stage x into LDS (one coalesced load)
    if (tid < GB * TT * NQ) x_s[tid] = x[(size_t)bbase * TT * NQ + tid];
    if (tid < GB * NQ) { h_s[tid] = 0.f; c_s[tid] = 0.f; }

    // ---- P1 mapping: job = g*81 + j; job1 = tid (<324), job2 = tid+320 (tid<4)
    const int g1 = tid / NP, jj1 = tid - g1 * NP;
    const bool has2 = tid < (GB * NP - NT);
    const int job2 = tid + NT;
    const int g2 = job2 / NP, jj2 = job2 - g2 * NP;

    float wh1[NQ], wh2[NQ];
#pragma unroll
    for (int k = 0; k < NQ; ++k) wh1[k] = Wh[k * NP + jj1];
    if (has2) {
#pragma unroll
        for (int k = 0; k < NQ; ++k) wh2[k] = Wh[k * NP + jj2];
    }

    // ---- stage B preload: wave = gate, lane = g*10+k (lanes 0..39 active)
    // gate order: 0=f(R0) 1=i(R1) 2=cand(R3) 3=mq(R4) 4=tm(R5)
    const bool hasB = (ln < GB * NQ);
    const int gB = ln / NQ, kB = ln - gB * NQ;
    const int gR = wv + (wv >= 2 ? 1 : 0);
    float rB[30];
    if (hasB) {
#pragma unroll
        for (int f = 0; f < 30; ++f) rB[f] = R[gR * 300 + f * 10 + kB];
    }

    // ---- stage C preload: constant o gate (circ_output feats = (0,1,0)^10)
    const bool hasC = tid < GB * NQ;
    float o_val = 0.f;
    if (hasC) {
        int kC = tid % NQ;
        float s = 0.f;
#pragma unroll
        for (int q = 0; q < NQ; ++q) s += R[600 + (3 * q + 1) * 10 + kC];
        o_val = sigm(s);
    }

    __syncthreads();

    // ---- hoist x@Wx + bias for all 8 timesteps into registers
    float px1[TT], px2[TT];
    {
        float wx[NQ];
#pragma unroll
        for (int k = 0; k < NQ; ++k) wx[k] = Wx[k * NP + jj1];
        float b = bias[jj1];
#pragma unroll
        for (int t = 0; t < TT; ++t) {
            float a = b;
#pragma unroll
            for (int k = 0; k < NQ; ++k) a = fmaf(x_s[g1 * 80 + t * 10 + k], wx[k], a);
            px1[t] = a;
        }
        if (has2) {
#pragma unroll
            for (int k = 0; k < NQ; ++k) wx[k] = Wx[k * NP + jj2];
            b = bias[jj2];
#pragma unroll
            for (int t = 0; t < TT; ++t) {
                float a = b;
#pragma unroll
                for (int k = 0; k < NQ; ++k) a = fmaf(x_s[g2 * 80 + t * 10 + k], wx[k], a);
                px2[t] = a;
            }
        }
    }

    for (int t = 0; t < TT; ++t) {
        // ================= P1: p = px[t] + h@Wh =================
        {
            const float* hh = &h_s[g1 * NQ];
            float a = px1[t];
#pragma unroll
            for (int k = 0; k < NQ; ++k) a = fmaf(hh[k], wh1[k], a);
            p_s[tid] = a;
            if (has2) {
                const float* hh2 = &h_s[g2 * NQ];
                float a2 = px2[t];
#pragma unroll
                for (int k = 0; k < NQ; ++k) a2 = fmaf(hh2[k], wh2[k], a2);
                p_s[job2] = a2;
            }
        }
        __syncthreads();

        // ================= A: one sincos per thread =================
        // unit u: 0..9 forget p[q]; 10..29 input p[10..29]; 30..49 cand
        // (b_q=p[41+3q], c_q=p[42+3q]); 50..59 memory p[70+q];
        // 60..63 temporal {.05,.10,.15,.20}*p[80]
        if (tid < 256) {
            const float* pp = &p_s[wv * NP];
            const int u = ln;
            float ang;
            if (u < 30) ang = pp[u];
            else if (u < 50) { int v = u - 30; ang = pp[41 + 3 * (v >> 1) + (v & 1)]; }
            else if (u < 60) ang = pp[u + 20];
            else ang = 0.05f * (float)(u - 59) * pp[80];
            float s, c;
            __sincosf(ang, &s, &c);
            sc_s[wv][u] = make_float2(s, c);
        }
        __syncthreads();

        // ================= B: features (closed form) + dot-30 =================
        if (hasB) {
            const float2* sc = sc_s[gB];
            float ft[30];
            if (wv == 0) {
                // forget: RY, CZ(2m,2m+1), T. partner = q^1
                float sa[NQ], ca[NQ];
#pragma unroll
                for (int q = 0; q < NQ; ++q) { sa[q] = sc[q].x; ca[q] = sc[q].y; }
                const float r2c = 0.70710678118654752f;
#pragma unroll
                for (int q = 0; q < NQ; ++q) {
                    ft[3 * q] = -sa[q];
                    float v = -r2c * ca[q] * sa[q ^ 1];
                    ft[3 * q + 1] = v; ft[3 * q + 2] = v;
                }
            } else if (wv == 1) {
                // input: RY,RZ + CNOT chain (prefix-XOR transfer matrices)
                float sa[NQ], xx[NQ], uu[NQ];
#pragma unroll
                for (int q = 0; q < NQ; ++q) {
                    float2 A = sc[10 + 2 * q], Bv = sc[11 + 2 * q];
                    sa[q] = A.x; xx[q] = A.y * Bv.y; uu[q] = A.y * Bv.x;
                }
                float Zprev = 1.f;
#pragma unroll
                for (int q = 0; q < NQ; ++q) {
                    float zq = Zprev * (-sa[q]);
                    float xn = (q < 9) ? xx[q + 1] : 1.f;
                    ft[3 * q] = zq;
                    ft[3 * q + 1] = xx[q] * xn;
                    ft[3 * q + 2] = uu[q] * Zprev * xn;
                    Zprev = zq;
                }
            } else if (wv == 2) {
                // candidate: H->|0..0>, RZ RY RZ, CZ graph
                // CAND_CZ: (0,2)(0,8)(0,9)(1,3)(1,6)(2,3)(2,4)(2,5)(2,6)(2,7)
                //          (2,9)(3,7)(4,6)(5,9)
                float sb[NQ], cb[NQ], scv[NQ], ccv[NQ];
#pragma unroll
                for (int q = 0; q < NQ; ++q) {
                    float2 Bv = sc[30 + 2 * q], Cv = sc[31 + 2 * q];
                    sb[q] = Bv.x; cb[q] = Bv.y; scv[q] = Cv.x; ccv[q] = Cv.y;
                }
                float P[NQ];
                P[0] = cb[2] * cb[8] * cb[9];
                P[1] = cb[3] * cb[6];
                P[2] = cb[0] * cb[3] * cb[4] * cb[5] * cb[6] * cb[7] * cb[9];
                P[3] = cb[1] * cb[2] * cb[7];
                P[4] = cb[2] * cb[6];
                P[5] = cb[2] * cb[9];
                P[6] = cb[1] * cb[2] * cb[4];
                P[7] = cb[2] * cb[3];
                P[8] = cb[0];
                P[9] = cb[0] * cb[2] * cb[5];
#pragma unroll
                for (int q = 0; q < NQ; ++q) {
                    ft[3 * q] = cb[q];
                    float m = sb[q] * P[q];
                    ft[3 * q + 1] = m * ccv[q];
                    ft[3 * q + 2] = m * scv[q];
                }
            } else if (wv == 3) {
                // memory: RY, CZ(2m,2m+1)
                float sa[NQ], ca[NQ];
#pragma unroll
                for (int q = 0; q < NQ; ++q) { sa[q] = sc[50 + q].x; ca[q] = sc[50 + q].y; }
#pragma unroll
                for (int q = 0; q < NQ; ++q) {
                    ft[3 * q] = -sa[q];
                    ft[3 * q + 1] = -ca[q] * sa[q ^ 1];
                    ft[3 * q + 2] = 0.f;
                }
            } else {
                // temporal: |0>|+>^9, RZ(0.1t) RX(0.05t), ZZ chain(0.2t)
                float s2 = sc[60].x, c2 = sc[60].y;
                float c4 = sc[61].y;
                float s6 = sc[62].x, c6 = sc[62].y;
                float s8 = sc[63].x, c8 = sc[63].y;
                float z0 = c2;
                float zs = 0.5f * (c2 - c6);
                float mre = 0.5f * c4;
                float mim = 0.25f * (s2 + s6);
                float E0re = c8, E0im = z0 * s8;
                float Esre = c8, Esim = zs * s8;
                float cr0re = 0.5f * s2 * Esim;
                float cr0im = -0.5f * s2 * Esre;
                float EEre = Esre * Esre - Esim * Esim, EEim = 2.f * Esre * Esim;
                float EOre = E0re * Esre - E0im * Esim, EOim = E0re * Esim + E0im * Esre;
                float cr1re = mre * EOre - mim * EOim, cr1im = mre * EOim + mim * EOre;
                float crmre = mre * EEre - mim * EEim, crmim = mre * EEim + mim * EEre;
                float cr9re = mre * Esre - mim * Esim, cr9im = mre * Esim + mim * Esre;
                ft[0] = z0; ft[1] = 2.f * cr0re; ft[2] = 2.f * cr0im;
                ft[3] = zs; ft[4] = 2.f * cr1re; ft[5] = 2.f * cr1im;
#pragma unroll
                for (int q = 2; q <= 8; ++q) {
                    ft[3 * q] = zs; ft[3 * q + 1] = 2.f * crmre; ft[3 * q + 2] = 2.f * crmim;
                }
                ft[27] = zs; ft[28] = 2.f * cr9re; ft[29] = 2.f * cr9im;
            }
            float acc = 0.f;
#pragma unroll
            for (int f = 0; f < 30; ++f) acc = fmaf(ft[f], rB[f], acc);
            g_s[wv * (GB * NQ) + ln] = acc;
        }
        __syncthreads();

        // ================= C: cell update =================
        if (hasC) {
            float f = sigm(g_s[0 * 40 + tid]);
            float ii = sigm(g_s[1 * 40 + tid]);
            float gg = tanh_(g_s[2 * 40 + tid]);
            float mq = sigm(g_s[3 * 40 + tid]);
            float tm = tanh_(g_s[4 * 40 + tid]);
            float cn = (f * c_s[tid] + ii * gg) * mq;
            float hn = o_val * tanh_(cn) + 0.1f * tm;
            c_s[tid] = cn;
            h_s[tid] = hn;
            int gC = tid / NQ, kC = tid - gC * NQ;
            out[(size_t)(bbase + gC) * (TT * NQ) + t * NQ + kC] = hn;
        }
        __syncthreads();
    }
}

extern "C" void kernel_launch(void* const* d_in, const int* in_sizes, int n_in,
                              void* d_out, int out_size, void* d_ws, size_t ws_size,
                              hipStream_t stream) {
    const float* x = (const float*)d_in[0];     // (2048, 8, 10) f32
    const float* Wx = (const float*)d_in[1];    // (10, 81)
    const float* Wh = (const float*)d_in[2];    // (10, 81)
    const float* bias = (const float*)d_in[3];  // (81,)
    const float* R = (const float*)d_in[4];     // (6, 30, 10)
    float* out = (float*)d_out;                 // (2048, 8, 10) f32

    qlstm_kernel<<<dim3(512), dim3(NT), 0, stream>>>(x, Wx, Wh, bias, R, out);
}

// Round 4
// 79.213 us; speedup vs baseline: 1.0481x; 1.0481x over previous
//
#include <hip/hip_runtime.h>

#define NQ 10
#define NP 81
#define TT 8

__device__ __forceinline__ float sigm(float z) {
    z = fminf(fmaxf(z, -30.f), 30.f);
    return 1.f / (1.f + __expf(-z));
}
__device__ __forceinline__ float tanh_(float z) {
    z = fminf(fmaxf(z, -15.f), 15.f);
    float e = __expf(2.f * z);
    return (e - 1.f) / (e + 1.f);
}

// One wave (64 threads) = one batch element through the whole T=8 scan.
// No cross-wave deps: all __syncthreads are single-wave (waitcnt-only cost).
// Lane u owns one needed p-column + one sincos unit:
//   u 0..9   forget angles   p[u]
//   u 10..29 input angles    p[u]            (RY,RZ interleaved)
//   u 30..49 cand angles     p[41+3q+comp]   (q=(u-30)>>1, comp=(u-30)&1)
//   u 50..59 memory angles   p[u+20]
//   u 60..63 temporal        {.05,.10,.15,.20}*p[80]
// Stage B: lane u<50 = (gate u/10, out k=u%10), R row in 30 regs.
// Stage C: lane k<10, cell state c kept in registers.
__global__ __launch_bounds__(64) void qlstm_kernel(
    const float* __restrict__ x, const float* __restrict__ Wx,
    const float* __restrict__ Wh, const float* __restrict__ bias,
    const float* __restrict__ R, float* __restrict__ out) {

    __shared__ float x_s[TT * NQ];   // this batch element's x, 80 floats
    __shared__ float4 scq[32];       // (s,c,s,c) pairs of the 64 sincos units
    __shared__ float g_s[50];        // gate pre-activations [gate*10+k]
    __shared__ float h_s[NQ];

    const int u = threadIdx.x;
    const size_t b = blockIdx.x;

    for (int i = u; i < TT * NQ; i += 64) x_s[i] = x[b * (TT * NQ) + i];
    if (u < NQ) h_s[u] = 0.f;

    // ---- column + angle-scale mapping
    int col;
    float scale = 1.f;
    if (u < 30) col = u;
    else if (u < 50) { int v = u - 30; col = 41 + 3 * (v >> 1) + (v & 1); }
    else if (u < 60) col = u + 20;
    else { col = 80; scale = 0.05f * (float)(u - 59); }

    float wx[NQ], wh[NQ];
#pragma unroll
    for (int k = 0; k < NQ; ++k) { wx[k] = Wx[k * NP + col]; wh[k] = Wh[k * NP + col]; }
    const float bj = bias[col];

    // ---- stage B preload: gate order 0=f(R0) 1=i(R1) 2=cand(R3) 3=mq(R4) 4=tm(R5)
    const bool hasB = u < 50;
    const int gate = u / 10, kB = u - (u / 10) * 10;
    const int gR = gate + (gate >= 2 ? 1 : 0);
    float rB[30];
    if (hasB) {
#pragma unroll
        for (int f = 0; f < 30; ++f) rB[f] = R[gR * 300 + f * 10 + kB];
    }

    // ---- stage C preload: constant o gate (circ_output feats = (0,1,0)^10)
    float o_val = 0.f, c = 0.f;
    if (u < NQ) {
        float s = 0.f;
#pragma unroll
        for (int q = 0; q < NQ; ++q) s += R[600 + (3 * q + 1) * 10 + u];
        o_val = sigm(s);
    }
    __syncthreads();

    // ---- hoist px[t] = bias + x_t@Wx (x_s reads are broadcast)
    float px[TT];
#pragma unroll
    for (int t = 0; t < TT; ++t) {
        float a = bj;
#pragma unroll
        for (int k = 0; k < NQ; ++k) a = fmaf(x_s[t * NQ + k], wx[k], a);
        px[t] = a;
    }

    for (int t = 0; t < TT; ++t) {
        // ===== P1 + A: p = px[t] + h@Wh ; one sincos per lane =====
        {
            float p = px[t];
#pragma unroll
            for (int k = 0; k < NQ; ++k) p = fmaf(h_s[k], wh[k], p);
            float s, cq;
            __sincosf(p * scale, &s, &cq);
            ((float2*)scq)[u] = make_float2(s, cq);
        }
        __syncthreads();

        // ===== B: closed-form features + dot-30 =====
        if (hasB) {
            float ft[30];
            if (gate == 0) {
                // forget: RY, CZ(2m,2m+1), T
                const float r2c = 0.70710678118654752f;
#pragma unroll
                for (int m = 0; m < 5; ++m) {
                    float4 F = scq[m];  // (sa,ca,sa',ca') for q=2m,2m+1
                    int q = 2 * m;
                    ft[3 * q] = -F.x;
                    float v = -r2c * F.y * F.z;
                    ft[3 * q + 1] = v; ft[3 * q + 2] = v;
                    ft[3 * q + 3] = -F.z;
                    float v2 = -r2c * F.w * F.x;
                    ft[3 * q + 4] = v2; ft[3 * q + 5] = v2;
                }
            } else if (gate == 1) {
                // input: RY,RZ + CNOT chain (prefix-XOR transfer matrices)
                float sa[NQ], xx[NQ], uu[NQ];
#pragma unroll
                for (int q = 0; q < NQ; ++q) {
                    float4 A = scq[5 + q];  // (sinA,cosA,sinB,cosB)
                    sa[q] = A.x; xx[q] = A.y * A.w; uu[q] = A.y * A.z;
                }
                float Zprev = 1.f;
#pragma unroll
                for (int q = 0; q < NQ; ++q) {
                    float zq = Zprev * (-sa[q]);
                    float xn = (q < 9) ? xx[q + 1] : 1.f;
                    ft[3 * q] = zq;
                    ft[3 * q + 1] = xx[q] * xn;
                    ft[3 * q + 2] = uu[q] * Zprev * xn;
                    Zprev = zq;
                }
            } else if (gate == 2) {
                // candidate: H->|0..0>, RZ RY RZ, CZ graph
                // CAND_CZ: (0,2)(0,8)(0,9)(1,3)(1,6)(2,3)(2,4)(2,5)(2,6)(2,7)
                //          (2,9)(3,7)(4,6)(5,9)
                float sb[NQ], cb[NQ], scv[NQ], ccv[NQ];
#pragma unroll
                for (int q = 0; q < NQ; ++q) {
                    float4 V = scq[15 + q];  // (sinB,cosB,sinC,cosC)
                    sb[q] = V.x; cb[q] = V.y; scv[q] = V.z; ccv[q] = V.w;
                }
                float P[NQ];
                P[0] = cb[2] * cb[8] * cb[9];
                P[1] = cb[3] * cb[6];
                P[2] = cb[0] * cb[3] * cb[4] * cb[5] * cb[6] * cb[7] * cb[9];
                P[3] = cb[1] * cb[2] * cb[7];
                P[4] = cb[2] * cb[6];
                P[5] = cb[2] * cb[9];
                P[6] = cb[1] * cb[2] * cb[4];
                P[7] = cb[2] * cb[3];
                P[8] = cb[0];
                P[9] = cb[0] * cb[2] * cb[5];
#pragma unroll
                for (int q = 0; q < NQ; ++q) {
                    ft[3 * q] = cb[q];
                    float m = sb[q] * P[q];
                    ft[3 * q + 1] = m * ccv[q];
                    ft[3 * q + 2] = m * scv[q];
                }
            } else if (gate == 3) {
                // memory: RY, CZ(2m,2m+1)
#pragma unroll
                for (int m = 0; m < 5; ++m) {
                    float4 M = scq[25 + m];  // (sa,ca,sa',ca')
                    int q = 2 * m;
                    ft[3 * q] = -M.x;
                    ft[3 * q + 1] = -M.y * M.z;
                    ft[3 * q + 2] = 0.f;
                    ft[3 * q + 3] = -M.z;
                    ft[3 * q + 4] = -M.w * M.x;
                    ft[3 * q + 5] = 0.f;
                }
            } else {
                // temporal: |0>|+>^9, RZ(0.1t) RX(0.05t), ZZ chain(0.2t)
                float4 T1 = scq[30];  // (s2,c2,s4,c4)
                float4 T2 = scq[31];  // (s6,c6,s8,c8)
                float s2 = T1.x, c2 = T1.y, c4 = T1.w;
                float s6 = T2.x, c6 = T2.y, s8 = T2.z, c8 = T2.w;
                float z0 = c2;
                float zs = 0.5f * (c2 - c6);
                float mre = 0.5f * c4;
                float mim = 0.25f * (s2 + s6);
                float E0re = c8, E0im = z0 * s8;
                float Esre = c8, Esim = zs * s8;
                float cr0re = 0.5f * s2 * Esim;
                float cr0im = -0.5f * s2 * Esre;
                float EEre = Esre * Esre - Esim * Esim, EEim = 2.f * Esre * Esim;
                float EOre = E0re * Esre - E0im * Esim, EOim = E0re * Esim + E0im * Esre;
                float cr1re = mre * EOre - mim * EOim, cr1im = mre * EOim + mim * EOre;
                float crmre = mre * EEre - mim * EEim, crmim = mre * EEim + mim * EEre;
                float cr9re = mre * Esre - mim * Esim, cr9im = mre * Esim + mim * Esre;
                ft[0] = z0; ft[1] = 2.f * cr0re; ft[2] = 2.f * cr0im;
                ft[3] = zs; ft[4] = 2.f * cr1re; ft[5] = 2.f * cr1im;
#pragma unroll
                for (int q = 2; q <= 8; ++q) {
                    ft[3 * q] = zs; ft[3 * q + 1] = 2.f * crmre; ft[3 * q + 2] = 2.f * crmim;
                }
                ft[27] = zs; ft[28] = 2.f * cr9re; ft[29] = 2.f * cr9im;
            }
            float acc = 0.f;
#pragma unroll
            for (int f = 0; f < 30; ++f) acc = fmaf(ft[f], rB[f], acc);
            g_s[u] = acc;
        }
        __syncthreads();

        // ===== C: cell update (c stays in registers of lanes 0..9) =====
        if (u < NQ) {
            float f = sigm(g_s[u]);
            float ii = sigm(g_s[10 + u]);
            float gg = tanh_(g_s[20 + u]);
            float mq = sigm(g_s[30 + u]);
            float tm = tanh_(g_s[40 + u]);
            c = (f * c + ii * gg) * mq;
            float hn = o_val * tanh_(c) + 0.1f * tm;
            h_s[u] = hn;
            out[b * (TT * NQ) + t * NQ + u] = hn;
        }
        __syncthreads();
    }
}

extern "C" void kernel_launch(void* const* d_in, const int* in_sizes, int n_in,
                              void* d_out, int out_size, void* d_ws, size_t ws_size,
                              hipStream_t stream) {
    const float* x = (const float*)d_in[0];     // (2048, 8, 10) f32
    const float* Wx = (const float*)d_in[1];    // (10, 81)
    const float* Wh = (const float*)d_in[2];    // (10, 81)
    const float* bias = (const float*)d_in[3];  // (81,)
    const float* R = (const float*)d_in[4];     // (6, 30, 10)
    float* out = (float*)d_out;                 // (2048, 8, 10) f32

    qlstm_kernel<<<dim3(2048), dim3(64), 0, stream>>>(x, Wx, Wh, bias, R, out);
}